// Round 3
// baseline (301.869 us; speedup 1.0000x reference)
//
#include <hip/hip_runtime.h>

// SelfAttention (SAGAN-style) on MI355X.
// B=2, C=64, C8=8, H=W=96, N=9216.  out = gamma * Attn(g,f,h) + x
//   K = f = (Wq/sq) x + bq   (pre-scaled by log2e; softmax in exp2 domain)
//   Q = g = (Wk/sk) x + bk
//   V = h = (Wv/sv) x + bv
// softmax over keys i; head_dim 8 (zero-padded to MFMA K=32), dv=64.
//
// R3: two-pass softmax with block-global per-query max. R2 pathology: ~8
// dependent DS ops (shfl/bpermute) per 32-key chunk in the online-softmax
// chain -> ~1000 cyc exposed latency/chunk -> 206 us. Now pass1 computes M
// (per-lane v_max only, one reduce at end, shared across waves via LDS), so
// pass2 has NO cross-lane ops except the P-transpose LDS round-trip, which is
// amortized over 64-key rounds. Final merge needs no exp (common M).

#define N_PIX 9216
#define N_B   2
#define N_C   64

typedef _Float16 half8  __attribute__((ext_vector_type(8)));
typedef _Float16 half4v __attribute__((ext_vector_type(4)));
typedef float    float4v __attribute__((ext_vector_type(4)));

#define LOG2E 1.44269504088896340736f

// ---------------------------------------------------------------- k_sigma
__global__ __launch_bounds__(64) void k_sigma(const float* __restrict__ Wq,
                                              const float* __restrict__ Wk,
                                              const float* __restrict__ Wv,
                                              float* __restrict__ sig) {
  __shared__ float G8[8][8];
  __shared__ float Wl[64 * 64];
  __shared__ _Float16 Wh[64 * 80];
  __shared__ _Float16 Gh[64 * 80];
  const int t = threadIdx.x;
  const int mat = blockIdx.x;
  if (mat < 2) {
    const float* W = (mat == 0) ? Wq : Wk;
    const int i = t >> 3, j = t & 7;
    float g = 0.f;
    for (int c = 0; c < 64; ++c) g += W[i * 64 + c] * W[j * 64 + c];
    G8[i][j] = g;
    __syncthreads();
    const int L = t & 7;
    float G0[8], Gr[8];
    for (int k = 0; k < 8; ++k) { G0[k] = G8[L][k]; Gr[k] = G0[k]; }
    for (int it = 0; it < 8; ++it) {
      float g2[8] = {0, 0, 0, 0, 0, 0, 0, 0};
      for (int k = 0; k < 8; ++k) {
        float gik = Gr[k];
        for (int jj = 0; jj < 8; ++jj) g2[jj] += gik * __shfl(Gr[jj], k, 64);
      }
      float mx = 0.f;
      for (int jj = 0; jj < 8; ++jj) mx = fmaxf(mx, fabsf(g2[jj]));
      for (int d = 1; d < 8; d <<= 1) mx = fmaxf(mx, __shfl_xor(mx, d, 64));
      float r = 1.f / mx;
      for (int jj = 0; jj < 8; ++jj) Gr[jj] = g2[jj] * r;
    }
    float u = 0.f;
    for (int jj = 0; jj < 8; ++jj) u += Gr[jj];
    float y = 0.f;
    for (int k = 0; k < 8; ++k) y += G0[k] * __shfl(u, k, 64);
    float nu = u * y, de = u * u;
    for (int d = 1; d < 8; d <<= 1) { nu += __shfl_xor(nu, d, 64); de += __shfl_xor(de, d, 64); }
    if (t == 0) sig[mat] = sqrtf(nu / de);
  } else {
    for (int idx = t; idx < 4096; idx += 64) Wl[idx] = Wv[idx];
    __syncthreads();
    for (int idx = t; idx < 4096; idx += 64) Wh[(idx >> 6) * 80 + (idx & 63)] = (_Float16)Wl[idx];
    __syncthreads();
    const int lane15 = t & 15, quad = t >> 4;
    half8 fr[4][2];
    for (int rb = 0; rb < 4; ++rb)
      for (int kc = 0; kc < 2; ++kc)
        fr[rb][kc] = *(const half8*)&Wh[(lane15 + 16 * rb) * 80 + 32 * kc + 8 * quad];
    float4v D[4][4];
    for (int mb = 0; mb < 4; ++mb) for (int nb = 0; nb < 4; ++nb) D[mb][nb] = (float4v){0.f, 0.f, 0.f, 0.f};
    for (int kc = 0; kc < 2; ++kc)
      for (int mb = 0; mb < 4; ++mb)
        for (int nb = 0; nb < 4; ++nb)
          D[mb][nb] = __builtin_amdgcn_mfma_f32_16x16x32_f16(fr[mb][kc], fr[nb][kc], D[mb][nb], 0, 0, 0);
    for (int it = 0; it < 8; ++it) {
      float mx = 0.f;
      for (int mb = 0; mb < 4; ++mb) for (int nb = 0; nb < 4; ++nb) for (int r = 0; r < 4; ++r)
        mx = fmaxf(mx, fabsf(D[mb][nb][r]));
      for (int d = 1; d < 64; d <<= 1) mx = fmaxf(mx, __shfl_xor(mx, d, 64));
      float rs = 1.f / mx;
      for (int mb = 0; mb < 4; ++mb) for (int nb = 0; nb < 4; ++nb) for (int r = 0; r < 4; ++r)
        Gh[(4 * quad + r + 16 * mb) * 80 + lane15 + 16 * nb] = (_Float16)(D[mb][nb][r] * rs);
      __syncthreads();
      if (it == 7) break;
      for (int rb = 0; rb < 4; ++rb)
        for (int kc = 0; kc < 2; ++kc)
          fr[rb][kc] = *(const half8*)&Gh[(lane15 + 16 * rb) * 80 + 32 * kc + 8 * quad];
      for (int mb = 0; mb < 4; ++mb) for (int nb = 0; nb < 4; ++nb) D[mb][nb] = (float4v){0.f, 0.f, 0.f, 0.f};
      for (int kc = 0; kc < 2; ++kc)
        for (int mb = 0; mb < 4; ++mb)
          for (int nb = 0; nb < 4; ++nb)
            D[mb][nb] = __builtin_amdgcn_mfma_f32_16x16x32_f16(fr[mb][kc], fr[nb][kc], D[mb][nb], 0, 0, 0);
      __syncthreads();
    }
    float u = 0.f;
    for (int c = 0; c < 64; ++c) u += (float)Gh[t * 80 + c];
    float z = 0.f;
    for (int i2 = 0; i2 < 64; ++i2) z += Wl[i2 * 64 + t] * __shfl(u, i2, 64);
    float nu = z * z, de = u * u;
    for (int d = 1; d < 64; d <<= 1) { nu += __shfl_xor(nu, d, 64); de += __shfl_xor(de, d, 64); }
    if (t == 0) sig[2] = sqrtf(nu / de);
  }
}

// ---------------------------------------------------------------- k_wconv
__global__ __launch_bounds__(128) void k_wconv(const float* __restrict__ Wq, const float* __restrict__ bq,
                                               const float* __restrict__ Wk, const float* __restrict__ bk,
                                               const float* __restrict__ Wv, const float* __restrict__ bv,
                                               const float* __restrict__ sig,
                                               _Float16* __restrict__ W16, float* __restrict__ b80) {
  const float iq = LOG2E / sig[0], ik = 1.0f / sig[1], iv = 1.0f / sig[2];
  const int t = threadIdx.x;
  for (int idx = t; idx < 80 * 64; idx += 128) {
    const int m = idx >> 6, c = idx & 63;
    float v;
    if (m < 8)       v = Wq[m * 64 + c] * iq;
    else if (m < 16) v = Wk[(m - 8) * 64 + c] * ik;
    else             v = Wv[(m - 16) * 64 + c] * iv;
    W16[idx] = (_Float16)v;
  }
  if (t < 80) {
    float v;
    if (t < 8)       v = bq[t] * LOG2E;
    else if (t < 16) v = bk[t - 8];
    else             v = bv[t - 16];
    b80[t] = v;
  }
}

// ---------------------------------------------------------------- k_fgh
__global__ __launch_bounds__(256) void k_fgh(const float* __restrict__ x,
                                             const _Float16* __restrict__ W16,
                                             const float* __restrict__ b80,
                                             _Float16* __restrict__ K16,
                                             _Float16* __restrict__ Q16,
                                             _Float16* __restrict__ VT16) {
  const int wave = threadIdx.x >> 6;
  const int lane = threadIdx.x & 63;
  const int lane15 = lane & 15, quad = lane >> 4;
  const int tile = blockIdx.x * 4 + wave;
  const int b = tile / 576;
  const int n = (tile % 576) * 16 + lane15;
  half8 wf[5][2];
  for (int mb = 0; mb < 5; ++mb)
    for (int kc = 0; kc < 2; ++kc)
      wf[mb][kc] = *(const half8*)&W16[(lane15 + 16 * mb) * 64 + 32 * kc + 8 * quad];
  float4v acc[5];
  for (int mb = 0; mb < 5; ++mb) acc[mb] = *(const float4v*)&b80[16 * mb + 4 * quad];
  const float* xb = x + (size_t)b * N_C * N_PIX;
  for (int kc = 0; kc < 2; ++kc) {
    half8 bf;
    for (int j = 0; j < 8; ++j)
      bf[j] = (_Float16)xb[(size_t)(32 * kc + 8 * quad + j) * N_PIX + n];
    for (int mb = 0; mb < 5; ++mb)
      acc[mb] = __builtin_amdgcn_mfma_f32_16x16x32_f16(wf[mb][kc], bf, acc[mb], 0, 0, 0);
  }
  {
    _Float16* dstK = K16 + ((size_t)b * N_PIX + n) * 8;
    _Float16* dstQ = Q16 + ((size_t)b * N_PIX + n) * 8;
    for (int r = 0; r < 4; ++r) {
      const int m = 4 * quad + r;
      const _Float16 v = (_Float16)acc[0][r];
      if (m < 8) dstK[m] = v; else dstQ[m - 8] = v;
    }
  }
  for (int mb = 1; mb < 5; ++mb)
    for (int r = 0; r < 4; ++r) {
      const int c = 4 * quad + r + 16 * (mb - 1);
      VT16[((size_t)b * N_C + c) * N_PIX + n] = (_Float16)acc[mb][r];
    }
}

// ---------------------------------------------------------------- k_attn
// Block = 4 waves, one 16-query tile; wave w covers keys [w*2304,(w+1)*2304).
// Pass1: per-query global max (MFMA + v_max only). Pass2: p=exp2(S-M), PV.
// 64-key rounds; K-frags double-buffered; V-frags loaded at round top.

#define KEYS_PER_WAVE (N_PIX / 4)   // 2304
#define ROUNDS        (KEYS_PER_WAVE / 64)  // 36

__device__ __forceinline__ void loadK4(half8 (&kf)[4], const _Float16* Kb,
                                       int i0, int lane15, int quad) {
#pragma unroll
  for (int t = 0; t < 4; ++t) {
    kf[t] = (half8){};
    if (quad == 0)
      kf[t] = *(const half8*)(Kb + (size_t)(i0 + 16 * t + lane15) * 8);
  }
}

__device__ __forceinline__ void p1_round(const half8 (&kf)[4], half8 (&kn)[4],
                                         bool prefK, int i1,
                                         const half8 qf, float& mloc,
                                         const _Float16* Kb, int lane15, int quad) {
  const float4v f4z = {0.f, 0.f, 0.f, 0.f};
  float4v s0 = __builtin_amdgcn_mfma_f32_16x16x32_f16(kf[0], qf, f4z, 0, 0, 0);
  float4v s1 = __builtin_amdgcn_mfma_f32_16x16x32_f16(kf[1], qf, f4z, 0, 0, 0);
  float4v s2 = __builtin_amdgcn_mfma_f32_16x16x32_f16(kf[2], qf, f4z, 0, 0, 0);
  float4v s3 = __builtin_amdgcn_mfma_f32_16x16x32_f16(kf[3], qf, f4z, 0, 0, 0);
  if (prefK) loadK4(kn, Kb, i1, lane15, quad);
#pragma unroll
  for (int r = 0; r < 4; ++r)
    mloc = fmaxf(mloc, fmaxf(fmaxf(s0[r], s1[r]), fmaxf(s2[r], s3[r])));
}

__device__ __forceinline__ void p2_round(const int i0,
                                         const half8 (&kf)[4], half8 (&kn)[4],
                                         bool prefK, int i1,
                                         const half8 qf, float4v (&acc)[4],
                                         float& lsum, const float M,
                                         const _Float16* Kb, const _Float16* Vb,
                                         _Float16* Pl, int lane15, int quad) {
  const float4v f4z = {0.f, 0.f, 0.f, 0.f};
  // V frags for this round: issued first, consumed ~300 cyc later by PV.
  half8 vf[8];
#pragma unroll
  for (int cb = 0; cb < 4; ++cb)
#pragma unroll
    for (int t2 = 0; t2 < 2; ++t2)
      vf[2 * cb + t2] = *(const half8*)(Vb + (size_t)(lane15 + 16 * cb) * N_PIX + i0 + 32 * t2 + 8 * quad);
  float4v s0 = __builtin_amdgcn_mfma_f32_16x16x32_f16(kf[0], qf, f4z, 0, 0, 0);
  float4v s1 = __builtin_amdgcn_mfma_f32_16x16x32_f16(kf[1], qf, f4z, 0, 0, 0);
  float4v s2 = __builtin_amdgcn_mfma_f32_16x16x32_f16(kf[2], qf, f4z, 0, 0, 0);
  float4v s3 = __builtin_amdgcn_mfma_f32_16x16x32_f16(kf[3], qf, f4z, 0, 0, 0);
  if (prefK) loadK4(kn, Kb, i1, lane15, quad);
  // p = exp2(S - M); per-lane lsum; pack to f16 in LDS (transpose to A-layout)
  float4v sv[4] = {s0, s1, s2, s3};
#pragma unroll
  for (int t = 0; t < 4; ++t) {
    half4v h;
#pragma unroll
    for (int r = 0; r < 4; ++r) {
      const float p = __builtin_amdgcn_exp2f(sv[t][r] - M);
      lsum += p;
      h[r] = (_Float16)p;
    }
    *(half4v*)&Pl[lane15 * 72 + 16 * t + 4 * quad] = h;
  }
  const half8 p0 = *(const half8*)&Pl[lane15 * 72 + 8 * quad];
  const half8 p1 = *(const half8*)&Pl[lane15 * 72 + 32 + 8 * quad];
#pragma unroll
  for (int cb = 0; cb < 4; ++cb) {
    acc[cb] = __builtin_amdgcn_mfma_f32_16x16x32_f16(p0, vf[2 * cb], acc[cb], 0, 0, 0);
    acc[cb] = __builtin_amdgcn_mfma_f32_16x16x32_f16(p1, vf[2 * cb + 1], acc[cb], 0, 0, 0);
  }
}

__global__ __launch_bounds__(256) void k_attn(const _Float16* __restrict__ K16,
                                              const _Float16* __restrict__ Q16,
                                              const _Float16* __restrict__ VT16,
                                              const float* __restrict__ x,
                                              const float* __restrict__ gamma,
                                              float* __restrict__ out) {
  __shared__ _Float16 P_lds[4][16 * 72];  // rows 144B (16B-aligned, 2-way banks = free)
  __shared__ float Msh[4][16];
  __shared__ float Lsh[4][16];
  __shared__ float Osh[4][64][17];        // +1 pad: conflict-free merge
  const int wave = threadIdx.x >> 6;
  const int lane = threadIdx.x & 63;
  const int lane15 = lane & 15, quad = lane >> 4;
  const int tile = blockIdx.x;            // 0..1151
  const int b = tile / 576;
  const int j0 = (tile % 576) * 16;
  const float gm = gamma[0];
  const _Float16* Kb = K16 + (size_t)b * N_PIX * 8;
  const _Float16* Vb = VT16 + (size_t)b * N_C * N_PIX;
  _Float16* Pl = P_lds[wave];
  const int kbeg = wave * KEYS_PER_WAVE;
  // Q frag (B-operand): lane holds Q[j0+lane15][k=8*quad+j]; real k only quad 0
  half8 qf = {};
  if (quad == 0) qf = *(const half8*)(Q16 + ((size_t)b * N_PIX + j0 + lane15) * 8);

  // ---------------- pass 1: per-query max over this wave's key range
  half8 kA[4], kB[4];
  loadK4(kA, Kb, kbeg, lane15, quad);
  float mloc = -1e30f;
#pragma unroll 1
  for (int r2 = 0; r2 < ROUNDS / 2; ++r2) {
    const int i0 = kbeg + r2 * 128;
    p1_round(kA, kB, true, i0 + 64, qf, mloc, Kb, lane15, quad);
    p1_round(kB, kA, r2 < ROUNDS / 2 - 1, i0 + 128, qf, mloc, Kb, lane15, quad);
  }
  mloc = fmaxf(mloc, __shfl_xor(mloc, 16, 64));
  mloc = fmaxf(mloc, __shfl_xor(mloc, 32, 64));
  if (quad == 0) Msh[wave][lane15] = mloc;
  __syncthreads();
  const float M = fmaxf(fmaxf(Msh[0][lane15], Msh[1][lane15]),
                        fmaxf(Msh[2][lane15], Msh[3][lane15]));  // global per-query max

  // ---------------- pass 2: p = exp2(S - M), acc += P V, lsum
  float4v acc[4];
  for (int cb = 0; cb < 4; ++cb) acc[cb] = (float4v){0.f, 0.f, 0.f, 0.f};
  float lsum = 0.f;
  loadK4(kA, Kb, kbeg, lane15, quad);
#pragma unroll 1
  for (int r2 = 0; r2 < ROUNDS / 2; ++r2) {
    const int i0 = kbeg + r2 * 128;
    p2_round(i0, kA, kB, true, i0 + 64, qf, acc, lsum, M, Kb, Vb, Pl, lane15, quad);
    p2_round(i0 + 64, kB, kA, r2 < ROUNDS / 2 - 1, i0 + 128, qf, acc, lsum, M, Kb, Vb, Pl, lane15, quad);
  }
  lsum += __shfl_xor(lsum, 16, 64);
  lsum += __shfl_xor(lsum, 32, 64);
  if (quad == 0) Lsh[wave][lane15] = lsum;
#pragma unroll
  for (int cb = 0; cb < 4; ++cb)
#pragma unroll
    for (int r = 0; r < 4; ++r) Osh[wave][lane][4 * cb + r] = acc[cb][r];
  __syncthreads();

  // ---------------- merge (no exp: all waves used the same M)
  const int c = lane15 + 16 * wave;
  const float* xb = x + (size_t)b * N_C * N_PIX;
  float* ob = out + (size_t)b * N_C * N_PIX;
  const int jq0 = 4 * quad;
  const float lst0 = Lsh[0][jq0] + Lsh[1][jq0] + Lsh[2][jq0] + Lsh[3][jq0];
  const float lst1 = Lsh[0][jq0 + 1] + Lsh[1][jq0 + 1] + Lsh[2][jq0 + 1] + Lsh[3][jq0 + 1];
  const float lst2 = Lsh[0][jq0 + 2] + Lsh[1][jq0 + 2] + Lsh[2][jq0 + 2] + Lsh[3][jq0 + 2];
  const float lst3 = Lsh[0][jq0 + 3] + Lsh[1][jq0 + 3] + Lsh[2][jq0 + 3] + Lsh[3][jq0 + 3];
  float4v osum = {0.f, 0.f, 0.f, 0.f};
#pragma unroll
  for (int w = 0; w < 4; ++w)
#pragma unroll
    for (int r = 0; r < 4; ++r) osum[r] += Osh[w][lane][4 * wave + r];
  const size_t idx = (size_t)c * N_PIX + j0 + jq0;
  const float4v xr = *(const float4v*)(xb + idx);
  float4v o;
  o[0] = gm * osum[0] / lst0 + xr[0];
  o[1] = gm * osum[1] / lst1 + xr[1];
  o[2] = gm * osum[2] / lst2 + xr[2];
  o[3] = gm * osum[3] / lst3 + xr[3];
  *(float4v*)(ob + idx) = o;
}

// ---------------------------------------------------------------- launch
extern "C" void kernel_launch(void* const* d_in, const int* in_sizes, int n_in,
                              void* d_out, int out_size, void* d_ws, size_t ws_size,
                              hipStream_t stream) {
  const float* x     = (const float*)d_in[0];
  const float* Wq    = (const float*)d_in[1];
  const float* bq    = (const float*)d_in[2];
  const float* Wk    = (const float*)d_in[3];
  const float* bk    = (const float*)d_in[4];
  const float* Wv    = (const float*)d_in[5];
  const float* bv    = (const float*)d_in[6];
  const float* gamma = (const float*)d_in[7];
  float* out = (float*)d_out;

  char* ws = (char*)d_ws;
  float*    sig  = (float*)ws;                       // 4 floats
  float*    b80  = (float*)(ws + 16);                // 80 floats
  _Float16* W16  = (_Float16*)(ws + 512);            // 80*64 halves
  _Float16* K16  = (_Float16*)(ws + 10752);          // 2*9216*8
  _Float16* Q16  = (_Float16*)(ws + 10752 + 294912); // 2*9216*8
  _Float16* VT16 = (_Float16*)(ws + 10752 + 2 * 294912); // 2*64*9216

  hipLaunchKernelGGL(k_sigma, dim3(3), dim3(64), 0, stream, Wq, Wk, Wv, sig);
  hipLaunchKernelGGL(k_wconv, dim3(1), dim3(128), 0, stream, Wq, bq, Wk, bk, Wv, bv, sig, W16, b80);
  hipLaunchKernelGGL(k_fgh, dim3(288), dim3(256), 0, stream, x, W16, b80, K16, Q16, VT16);
  hipLaunchKernelGGL(k_attn, dim3(1152), dim3(256), 0, stream, K16, Q16, VT16, x, gamma, out);
}